// Round 17
// baseline (1920.987 us; speedup 1.0000x reference)
//
#include <hip/hip_runtime.h>
#include <hip/hip_bf16.h>
#include <cstdint>

#define B 2048
#define NL 32
#define FEAT 512
#define HID 512
#define HW 64
#define OUTSZ 42
#define G3 1536
#define LDIH 554   // gru_w_ih row stride
#define MB 16      // batch rows per block
#define NBLK (B/MB)   // 128
#define LDX 584    // lds_x row stride (cols 554..583 stay zero -> zero-pad region)
#define LDH 520    // o1s row stride
#define CPS 144    // 16KB chunks per step: 108 A + 32 B + 4 C
#define CW 8192    // bf16 elements per 16KB chunk

typedef __bf16 bf16x8 __attribute__((ext_vector_type(8)));
typedef unsigned short u16x8 __attribute__((ext_vector_type(8)));
typedef float f32x4 __attribute__((ext_vector_type(4)));
typedef __hip_bfloat16 bf16_t;

#define MFMA(a,b,c) __builtin_amdgcn_mfma_f32_16x16x32_bf16(a,b,c,0,0,0)

// Per-wave pacing: chunk gc landed when outstanding <= 8 (chunks gc+1..gc+4).
#define WAITV8() asm volatile("s_waitcnt vmcnt(8)" ::: "memory")
// Phase boundary: publish this wave's ds ops, RAW barrier (prefetches stay in flight).
#define PHASE_SYNC() do {                                            \
    asm volatile("s_waitcnt lgkmcnt(0)" ::: "memory");               \
    __builtin_amdgcn_s_barrier();                                    \
  } while (0)
// Before phase C: C chunks are consumed cross-wave -> all ring loads must land.
#define PHASE_SYNC_V0() do {                                         \
    asm volatile("s_waitcnt vmcnt(0) lgkmcnt(0)" ::: "memory");      \
    __builtin_amdgcn_s_barrier();                                    \
  } while (0)

static __device__ __forceinline__ float sigmoidf_(float x){ return 1.f/(1.f+__expf(-x)); }

static __device__ __forceinline__ void gld16(const bf16_t* g, bf16_t* l){
  __builtin_amdgcn_global_load_lds(
      (const __attribute__((address_space(1))) void*)g,
      (__attribute__((address_space(3))) void*)l, 16, 0, 0);
}

// ---------------- one-time weight prep into 16KB-chunk STAGING layouts ----------------
// sA16[108][512][16]: chunk c = k0*6 + g*2 + kh holds W[g*512+rp][k0*32+kh*16 .. +16].
//   Granule gq (8 bf16) of row rp holds logical fragment f = gq ^ ((rp>>2)&1)
//   -> active-quarter ds_read_b128 is 2-way bank-free.
// sB16[32][512][16]: chunk c = kb*2 + kh of lin1, same granule swizzle.
// sC4[4][64][128]: chunk n holds lin2 k n*128..+128; granule gq2 (of 16) holds
//   sG = gq2 ^ (j&7) -> cross-row reads bank-free. rows 42..63 zero.
// w_ssn[512][64]; w_ih512b, bias_comb: preamble GEMM.
__global__ __launch_bounds__(256) void prep5_kernel(
    const float* __restrict__ w_ih, const float* __restrict__ w_hh,
    const float* __restrict__ lin1_w, const float* __restrict__ lin2_w,
    const float* __restrict__ b_ih, const float* __restrict__ b_hh,
    bf16_t* __restrict__ sA, bf16_t* __restrict__ sB, bf16_t* __restrict__ sC,
    bf16_t* __restrict__ w_ssn, bf16_t* __restrict__ w_ih512b,
    float* __restrict__ bias_comb){
  const int NA = 108*CW, NB2 = 32*CW, NC2 = 4*CW, NS = 512*64, NI = G3*512;
  const int total = NA+NB2+NC2+NS+NI+G3;
  for (int idx = blockIdx.x*256 + threadIdx.x; idx < total; idx += gridDim.x*256){
    int i = idx;
    if (i < NA){
      int c = i/CW, r2 = i%CW, rp = r2>>4, kk = r2&15, gq = kk>>3, e = kk&7;
      int k0 = c/6, rem = c%6, g = rem>>1, kh = rem&1;
      int f = gq ^ ((rp>>2)&1);
      int k = k0*32 + kh*16 + f*8 + e;
      int orow = g*512 + rp;
      float v = (k < 512) ? w_hh[orow*512 + k]
              : ((k < 512+OUTSZ && g < 2) ? w_ih[(size_t)orow*LDIH + k] : 0.f);
      sA[i] = __float2bfloat16(v);
    } else if ((i -= NA) < NB2){
      int c = i/CW, r2 = i%CW, rp = r2>>4, kk = r2&15, gq = kk>>3, e = kk&7;
      int kb = c>>1, kh = c&1;
      int f = gq ^ ((rp>>2)&1);
      int k = kb*32 + kh*16 + f*8 + e;
      sB[i] = __float2bfloat16(lin1_w[rp*512 + k]);
    } else if ((i -= NB2) < NC2){
      int n = i/CW, r2 = i%CW, j = r2>>7, kk = r2&127, gq2 = kk>>3, e = kk&7;
      int sG = gq2 ^ (j & 7);
      int k = n*128 + sG*8 + e;
      float v = (j < OUTSZ) ? lin2_w[j*512 + k] : 0.f;
      sC[i] = __float2bfloat16(v);
    } else if ((i -= NC2) < NS){
      int j = i>>6, k = i&63;
      float v = (k < OUTSZ) ? w_ih[(size_t)(1024+j)*LDIH + 512 + k] : 0.f;
      w_ssn[i] = __float2bfloat16(v);
    } else if ((i -= NS) < NI){
      int r = i>>9, c = i&511;
      w_ih512b[i] = __float2bfloat16(w_ih[(size_t)r*LDIH + c]);
    } else {
      int j = i - NI;
      bias_comb[j] = b_ih[j] + (j < 1024 ? b_hh[j] : 0.f);
    }
  }
}

// ---------------- attention precompute (step-invariant) ----------------
__global__ __launch_bounds__(256) void att_kernel(const float* __restrict__ feat,
                                                  const float* __restrict__ att_w,
                                                  bf16_t* __restrict__ att_feat){
  int b = blockIdx.x;
  const float* fb = feat + (size_t)b * FEAT * HW;
  __shared__ float part[4][64];
  __shared__ float attv[64];
  int t = threadIdx.x;
  int s = t & 63, q = t >> 6;
  float acc = 0.f;
  for (int c = q*128; c < q*128 + 128; ++c)
    acc = fmaf(fb[c*HW + s], att_w[c], acc);
  part[q][s] = acc;
  __syncthreads();
  if (t < 64){
    float v = part[0][t] + part[1][t] + part[2][t] + part[3][t];
    float m = v;
    for (int o = 32; o > 0; o >>= 1) m = fmaxf(m, __shfl_xor(m, o));
    float e = __expf(v - m);
    float ssum = e;
    for (int o = 32; o > 0; o >>= 1) ssum += __shfl_xor(ssum, o);
    attv[t] = e / ssum * 2.0f;   // * BETA
  }
  __syncthreads();
  for (int c = t; c < FEAT; c += 256){
    const float4* row = (const float4*)(fb + c*HW);
    float a2 = 0.f;
    #pragma unroll
    for (int k = 0; k < 16; ++k){
      float4 v4 = row[k];
      a2 = fmaf(v4.x, attv[k*4+0], a2);
      a2 = fmaf(v4.y, attv[k*4+1], a2);
      a2 = fmaf(v4.z, attv[k*4+2], a2);
      a2 = fmaf(v4.w, attv[k*4+3], a2);
    }
    att_feat[(size_t)b*FEAT + c] = __float2bfloat16(a2);
  }
}

// ---------------- bf16 MFMA GEMM (NT) for gi_base preamble ----------------
__global__ __launch_bounds__(256) void gemm_mfma(const bf16_t* __restrict__ A,
                                                 const bf16_t* __restrict__ W,
                                                 const float* __restrict__ bias,
                                                 float* __restrict__ C,
                                                 int K, int lda, int ldw, int ldc){
  const int tid = threadIdx.x;
  const int w = tid >> 6, lane = tid & 63;
  const int r = lane & 15, half = lane >> 4;
  const int m_base = blockIdx.y * 64;
  const int n_base = blockIdx.x * 64 + w * 16;
  const bf16_t* Ap = A + (size_t)(m_base + r)*lda + half*8;
  const bf16_t* Wp = W + (size_t)(n_base + r)*ldw + half*8;
  f32x4 acc[4] = {};
  for (int k0 = 0; k0 < K; k0 += 32){
    bf16x8 bfrag = *(const bf16x8*)(Wp + k0);
    #pragma unroll
    for (int i = 0; i < 4; ++i){
      bf16x8 afrag = *(const bf16x8*)(Ap + (size_t)i*16*lda + k0);
      acc[i] = MFMA(afrag, bfrag, acc[i]);
    }
  }
  const float bv = bias ? bias[n_base + r] : 0.f;
  #pragma unroll
  for (int i = 0; i < 4; ++i)
    #pragma unroll
    for (int q = 0; q < 4; ++q)
      C[(size_t)(m_base + i*16 + half*4 + q)*ldc + n_base + r] = acc[i][q] + bv;
}

// ---------------- the 32-step scan: 6-slot 16KB ring, depth-5 wave-private pipeline ----
// Per 16KB chunk (one 16-k half): lanes of the other k-half get zero B-fragments
// (broadcast read from lds_x's zero pad), so the verified K=32 MFMA computes a
// correct partial sum. WAITV(8) + issue(gc+5): 5-chunk prefetch lead per wave.
__global__ __launch_bounds__(512, 2) void mega14_kernel(
    const float* __restrict__ gi_base,
    const bf16_t* __restrict__ sA,
    const bf16_t* __restrict__ sB,
    const bf16_t* __restrict__ sC,
    const bf16_t* __restrict__ w_ssn,
    const float* __restrict__ lin1_b,
    const float* __restrict__ lin2_b,
    const float* __restrict__ b_hh,
    const float* __restrict__ gt,
    const int* __restrict__ line_prob,
    const float* __restrict__ sample_prob,
    float* __restrict__ out){
  __shared__ bf16_t ring[6*CW];          // 6 x 16KB, wave-sliced
  __shared__ bf16_t lds_x[MB][LDX];      // [h(512) | ss(42) | zeros(pad->bfrag zero src)]
  __shared__ bf16_t o1s[MB][LDH];
  const int tid = threadIdx.x;
  const int wv = tid >> 6, l = tid & 63;
  const int lr = l & 15, half = l >> 4;
  const int m0 = blockIdx.x * MB;
  const int colbase = wv * 64;
  const bool lowk = (half < 2);          // lane's k-half within a 32-k block

  for (int i = tid; i < MB*LDX/2; i += 512) ((uint32_t*)lds_x)[i] = 0u;

  // per-ti staged-read offsets (elements) within a chunk slot; p is lane-constant
  const int p8 = ((half & 1) ^ ((lr >> 2) & 1)) * 8;
  int rdoff[4];
  #pragma unroll
  for (int ti = 0; ti < 4; ++ti)
    rdoff[ti] = (colbase + ti*16 + lr)*16 + p8;
  const bf16_t* zptr = &lds_x[0][560];   // 16B-aligned, stays zero forever

  // ---- register-resident gi_base slice: 4(ti) x 4(q) x 3 gates ----
  float gir[4][4], giz[4][4], gin_[4][4];
  #pragma unroll
  for (int ti = 0; ti < 4; ++ti)
    #pragma unroll
    for (int q = 0; q < 4; ++q){
      const float* gp = gi_base + (size_t)(m0 + half*4 + q)*G3 + colbase + ti*16 + lr;
      gir[ti][q]  = gp[0];
      giz[ti][q]  = gp[512];
      gin_[ti][q] = gp[1024];
    }
  float bhn[4], lb1[4];
  #pragma unroll
  for (int ti = 0; ti < 4; ++ti){
    bhn[ti] = b_hh[1024 + colbase + ti*16 + lr];
    lb1[ti] = lin1_b[colbase + ti*16 + lr];
  }
  const int j3 = wv*16 + lr;
  const float b2c = (wv < 3 && j3 < OUTSZ) ? lin2_b[j3] : 0.f;
  bf16x8 sfr[4][2];
  #pragma unroll
  for (int ti = 0; ti < 4; ++ti)
    #pragma unroll
    for (int ks = 0; ks < 2; ++ks)
      sfr[ti][ks] = *(const bf16x8*)(w_ssn + (size_t)(colbase + ti*16 + lr)*64 + ks*32 + half*8);

  float hp[4][4] = {};

  // Wave-private slice issue: wave wv loads its 1KB x2 of chunk g into slot g%6.
  auto issue = [&](uint32_t g){
    const bf16_t* src = sA;              // dummy tail issues read sA
    if (g < (uint32_t)NL*CPS){
      uint32_t c = g % CPS;
      src = (c < 108) ? sA + (size_t)c*CW
          : (c < 140) ? sB + (size_t)(c-108)*CW
                      : sC + (size_t)(c-140)*CW;
    }
    const int off = wv*1024 + l*8;
    const bf16_t* s = src + off;
    bf16_t* dst = ring + (g % 6)*CW + off;
    gld16(s, dst);
    gld16(s + 512, dst + 512);
  };

  __syncthreads();                       // lds_x zeros visible (zptr region!)
  uint32_t gc = 0;
  issue(0); issue(1); issue(2); issue(3); issue(4);

  #pragma unroll 1
  for (int t = 0; t < NL; ++t){
    // ============ phase A: 108 chunk-ticks, barrier-free, depth-5 ============
    f32x4 accA[3][4] = {};
    #pragma unroll 1
    for (int k0 = 0; k0 < 18; ++k0){
      bf16x8 a = *(const bf16x8*)&lds_x[lr][k0*32 + half*8];
      #pragma unroll
      for (int g = 0; g < 3; ++g){
        #pragma unroll
        for (int kh = 0; kh < 2; ++kh){
          WAITV8();                      // chunk gc landed
          issue(gc + 5);                 // slot(gc-1): consumed+drained last tick
          const bf16_t* S = ring + (gc % 6)*CW;
          const bool act = (kh == 0) ? lowk : !lowk;
          #pragma unroll
          for (int ti = 0; ti < 4; ++ti){
            const bf16_t* bp = act ? (S + rdoff[ti]) : zptr;
            bf16x8 bf = *(const bf16x8*)bp;
            accA[g][ti] = MFMA(a, bf, accA[g][ti]);
          }
          ++gc;
        }
      }
    }

    // ---- ssn (weights in VGPRs; reads lds_x ss cols) ----
    f32x4 accS[4] = {};
    #pragma unroll
    for (int ks = 0; ks < 2; ++ks){
      bf16x8 a2 = *(const bf16x8*)&lds_x[lr][512 + ks*32 + half*8];
      #pragma unroll
      for (int ti = 0; ti < 4; ++ti)
        accS[ti] = MFMA(a2, sfr[ti][ks], accS[ti]);
    }
    PHASE_SYNC();    // (1) all waves' lds_x reads done before gates rewrite h

    // ---- gates ----
    #pragma unroll
    for (int ti = 0; ti < 4; ++ti)
      #pragma unroll
      for (int q = 0; q < 4; ++q){
        float ir = accA[0][ti][q] + gir[ti][q];
        float iz = accA[1][ti][q] + giz[ti][q];
        float hn = accA[2][ti][q] + bhn[ti];
        float gn = gin_[ti][q] + accS[ti][q];
        float r = sigmoidf_(ir);
        float z = sigmoidf_(iz);
        float n = tanhf(gn + r*hn);
        float hv = (1.f - z)*n + z*hp[ti][q];
        hp[ti][q] = hv;
        lds_x[half*4 + q][colbase + ti*16 + lr] = __float2bfloat16(hv);
      }
    PHASE_SYNC();    // (2) h visible to all waves

    // ============ phase B: 32 chunk-ticks, barrier-free, depth-5 ============
    f32x4 accB[4] = {};
    #pragma unroll 1
    for (int kb = 0; kb < 16; ++kb){
      union { u16x8 u; bf16x8 b; } va;
      va.u = *(const u16x8*)&lds_x[lr][kb*32 + half*8];
      #pragma unroll
      for (int e = 0; e < 8; ++e)
        if (va.u[e] & 0x8000) va.u[e] = 0;       // relu on bf16 sign
      #pragma unroll
      for (int kh = 0; kh < 2; ++kh){
        WAITV8();
        issue(gc + 5);
        const bf16_t* S = ring + (gc % 6)*CW;
        const bool act = (kh == 0) ? lowk : !lowk;
        #pragma unroll
        for (int ti = 0; ti < 4; ++ti){
          const bf16_t* bp = act ? (S + rdoff[ti]) : zptr;
          bf16x8 bf = *(const bf16x8*)bp;
          accB[ti] = MFMA(va.b, bf, accB[ti]);
        }
        ++gc;
      }
    }
    #pragma unroll
    for (int ti = 0; ti < 4; ++ti)
      #pragma unroll
      for (int q = 0; q < 4; ++q)
        o1s[half*4 + q][colbase + ti*16 + lr] =
            __float2bfloat16(fmaxf(accB[ti][q] + lb1[ti], 0.f));
    PHASE_SYNC_V0(); // (3) o1s visible AND all ring loads landed (C is cross-slice)

    // ============ phase C: 4 chunks (lin2), pre-drained, NO ISSUES ============
    f32x4 accC = {};
    #pragma unroll
    for (int n = 0; n < 4; ++n){
      if (wv < 3){
        const bf16_t* S = ring + (gc % 6)*CW;
        #pragma unroll
        for (int k0l = 0; k0l < 4; ++k0l){
          bf16x8 a = *(const bf16x8*)&o1s[lr][(n*4 + k0l)*32 + half*8];
          int sg = (k0l*4 + half) ^ (j3 & 7);
          bf16x8 bf = *(const bf16x8*)&S[j3*128 + sg*8];
          accC = MFMA(a, bf, accC);
        }
      }
      ++gc;
    }
    // outputs + ss_{t+1}
    if (wv < 3){
      #pragma unroll
      for (int q = 0; q < 4; ++q){
        float val = accC[q] + b2c;
        int row = half*4 + q;
        int bm = m0 + row;
        if (j3 < 40){
          out[((size_t)bm*NL + t)*40 + j3] = val;
        } else if (j3 < 42){
          float other = __shfl_xor(val, 1);
          float mx = fmaxf(val, other);
          float e0 = __expf(val - mx), e1 = __expf(other - mx);
          out[(size_t)B*NL*40 + ((size_t)bm*NL + t)*2 + (j3 - 40)] = e0/(e0 + e1);
        }
        if (t + 1 < NL && j3 < OUTSZ){
          bool up = sample_prob[(size_t)(t+1)*B + bm] < 0.1f;
          float gtv;
          if (j3 < 40) gtv = gt[((size_t)bm*NL + t)*40 + j3];
          else {
            float pv = (float)line_prob[bm*NL + t];
            gtv = (j3 == 40) ? 1.f - pv : pv;
          }
          lds_x[row][512 + j3] = __float2bfloat16(up ? val : gtv);
        }
      }
    }
    PHASE_SYNC();    // (4) ss visible; all C readers drained -> slots reusable
    // refill pipeline for next step: chunk gc(=next A0) was issued during B;
    // issue gc+1..gc+4 now (slots held B-last/C chunks, consumed+drained above).
    issue(gc + 1); issue(gc + 2); issue(gc + 3); issue(gc + 4);
  }
}

extern "C" void kernel_launch(void* const* d_in, const int* in_sizes, int n_in,
                              void* d_out, int out_size, void* d_ws, size_t ws_size,
                              hipStream_t stream) {
  const float* img         = (const float*)d_in[0];
  const float* gt          = (const float*)d_in[1];
  const int*   line_prob   = (const int*)d_in[2];
  const float* sample_prob = (const float*)d_in[3];
  const float* att_w       = (const float*)d_in[4];
  // d_in[5] att_b: unused — softmax shift-invariance cancels it
  const float* w_ih        = (const float*)d_in[6];
  const float* w_hh        = (const float*)d_in[7];
  const float* b_ih        = (const float*)d_in[8];
  const float* b_hh        = (const float*)d_in[9];
  const float* lin1_w      = (const float*)d_in[10];
  const float* lin1_b      = (const float*)d_in[11];
  const float* lin2_w      = (const float*)d_in[12];
  const float* lin2_b      = (const float*)d_in[13];
  float* out = (float*)d_out;

  char* p = (char*)d_ws;
  auto alloc = [&](size_t bytes){ void* q = p; p += (bytes + 255) & ~(size_t)255; return q; };
  float*  gi_base   = (float*)alloc((size_t)B*G3*4);
  bf16_t* att_bf    = (bf16_t*)alloc((size_t)B*FEAT*2);
  bf16_t* sA        = (bf16_t*)alloc((size_t)108*CW*2);
  bf16_t* sB        = (bf16_t*)alloc((size_t)32*CW*2);
  bf16_t* sC        = (bf16_t*)alloc((size_t)4*CW*2);
  bf16_t* w_ssn     = (bf16_t*)alloc((size_t)512*64*2);
  bf16_t* w_ih512b  = (bf16_t*)alloc((size_t)G3*512*2);
  float*  bias_comb = (float*)alloc((size_t)G3*4);

  prep5_kernel<<<4096, 256, 0, stream>>>(w_ih, w_hh, lin1_w, lin2_w, b_ih, b_hh,
                                         sA, sB, sC, w_ssn, w_ih512b, bias_comb);
  att_kernel<<<B, 256, 0, stream>>>(img, att_w, att_bf);
  gemm_mfma<<<dim3(G3/64, B/64), 256, 0, stream>>>(att_bf, w_ih512b, bias_comb, gi_base,
                                                   512, 512, 512, G3);
  mega14_kernel<<<NBLK, 512, 0, stream>>>(gi_base, sA, sB, sC, w_ssn, lin1_b, lin2_b,
                                          b_hh, gt, line_prob, sample_prob, out);
}

// Round 18
// 1467.020 us; speedup vs baseline: 1.3094x; 1.3094x over previous
//
#include <hip/hip_runtime.h>
#include <hip/hip_bf16.h>
#include <cstdint>

#define B 2048
#define NL 32
#define FEAT 512
#define HID 512
#define HW 64
#define OUTSZ 42
#define G3 1536
#define LDIH 554   // gru_w_ih row stride
#define MB 16      // batch rows per block
#define NBLK (B/MB)   // 128
#define LDX 584    // lds_x row stride
#define LDH 520    // o1s row stride
#define CPS 72     // chunks per step: 54 A + 16 B + 2 C
#define CHW 16384  // bf16 elements per 32KB chunk

typedef __bf16 bf16x8 __attribute__((ext_vector_type(8)));
typedef unsigned short u16x8 __attribute__((ext_vector_type(8)));
typedef float f32x4 __attribute__((ext_vector_type(4)));
typedef __hip_bfloat16 bf16_t;

#define MFMA(a,b,c) __builtin_amdgcn_mfma_f32_16x16x32_bf16(a,b,c,0,0,0)

// Per-wave pacing: each wave issues 2 gld16 per chunk. Before consuming chunk
// gc, outstanding = {gc:2, gc+1:2} -> wait vmcnt(2) means gc landed.
#define WAITV2() asm volatile("s_waitcnt vmcnt(2)" ::: "memory")
// Phase boundary: publish this wave's ds ops, RAW barrier (prefetches stay in flight).
#define PHASE_SYNC() do {                                            \
    asm volatile("s_waitcnt lgkmcnt(0)" ::: "memory");               \
    __builtin_amdgcn_s_barrier();                                    \
  } while (0)
// Before phase C: C chunks are consumed cross-wave -> all ring loads must land.
#define PHASE_SYNC_V0() do {                                         \
    asm volatile("s_waitcnt vmcnt(0) lgkmcnt(0)" ::: "memory");      \
    __builtin_amdgcn_s_barrier();                                    \
  } while (0)

static __device__ __forceinline__ float sigmoidf_(float x){ return 1.f/(1.f+__expf(-x)); }

static __device__ __forceinline__ void gld16(const bf16_t* g, bf16_t* l){
  __builtin_amdgcn_global_load_lds(
      (const __attribute__((address_space(1))) void*)g,
      (__attribute__((address_space(3))) void*)l, 16, 0, 0);
}

// ---------------- one-time weight prep into STAGING layouts (verified) ----------------
// sA[54][512][32]: chunk (k0,g) at c=k0*3+g; row rp; granule gq holds
//   k-quarter half = gq ^ ((rp>>1)&3)  -> conflict-free wave-wide ds_read_b128.
// sB[16][512][32]: lin1 chunks. sC[2][64][256]: lin2 k-halves, granule s holds
//   g = s^(j&7). w_ssn[512][64]; w_ih512b, bias_comb: preamble GEMM.
__global__ __launch_bounds__(256) void prep4_kernel(
    const float* __restrict__ w_ih, const float* __restrict__ w_hh,
    const float* __restrict__ lin1_w, const float* __restrict__ lin2_w,
    const float* __restrict__ b_ih, const float* __restrict__ b_hh,
    bf16_t* __restrict__ sA, bf16_t* __restrict__ sB, bf16_t* __restrict__ sC,
    bf16_t* __restrict__ w_ssn, bf16_t* __restrict__ w_ih512b,
    float* __restrict__ bias_comb){
  const int NA = 54*CHW, NB2 = 16*CHW, NC2 = 2*CHW, NS = 512*64, NI = G3*512;
  const int total = NA+NB2+NC2+NS+NI+G3;
  for (int idx = blockIdx.x*256 + threadIdx.x; idx < total; idx += gridDim.x*256){
    int i = idx;
    if (i < NA){
      int c = i/CHW, r2 = i%CHW, rp = r2>>5, kk = r2&31, gq = kk>>3, e = kk&7;
      int k0 = c/3, g = c%3;
      int half = gq ^ ((rp>>1)&3);
      int orow = g*512 + rp;
      int k = k0*32 + half*8 + e;
      float v = (k < 512) ? w_hh[orow*512 + k]
              : ((k < 512+OUTSZ && g < 2) ? w_ih[(size_t)orow*LDIH + k] : 0.f);
      sA[i] = __float2bfloat16(v);
    } else if ((i -= NA) < NB2){
      int c = i/CHW, r2 = i%CHW, rp = r2>>5, kk = r2&31, gq = kk>>3, e = kk&7;
      int half = gq ^ ((rp>>1)&3);
      sB[i] = __float2bfloat16(lin1_w[rp*512 + c*32 + half*8 + e]);
    } else if ((i -= NB2) < NC2){
      int n = i/CHW, r2 = i%CHW, j = r2>>8, kk = r2&255, s = kk>>3, e = kk&7;
      int g = s ^ (j & 7);
      int k = n*256 + g*8 + e;
      float v = (j < OUTSZ) ? lin2_w[j*512 + k] : 0.f;
      sC[i] = __float2bfloat16(v);
    } else if ((i -= NC2) < NS){
      int j = i>>6, k = i&63;
      float v = (k < OUTSZ) ? w_ih[(size_t)(1024+j)*LDIH + 512 + k] : 0.f;
      w_ssn[i] = __float2bfloat16(v);
    } else if ((i -= NS) < NI){
      int r = i>>9, c = i&511;
      w_ih512b[i] = __float2bfloat16(w_ih[(size_t)r*LDIH + c]);
    } else {
      int j = i - NI;
      bias_comb[j] = b_ih[j] + (j < 1024 ? b_hh[j] : 0.f);
    }
  }
}

// ---------------- attention precompute (step-invariant) ----------------
__global__ __launch_bounds__(256) void att_kernel(const float* __restrict__ feat,
                                                  const float* __restrict__ att_w,
                                                  bf16_t* __restrict__ att_feat){
  int b = blockIdx.x;
  const float* fb = feat + (size_t)b * FEAT * HW;
  __shared__ float part[4][64];
  __shared__ float attv[64];
  int t = threadIdx.x;
  int s = t & 63, q = t >> 6;
  float acc = 0.f;
  for (int c = q*128; c < q*128 + 128; ++c)
    acc = fmaf(fb[c*HW + s], att_w[c], acc);
  part[q][s] = acc;
  __syncthreads();
  if (t < 64){
    float v = part[0][t] + part[1][t] + part[2][t] + part[3][t];
    float m = v;
    for (int o = 32; o > 0; o >>= 1) m = fmaxf(m, __shfl_xor(m, o));
    float e = __expf(v - m);
    float ssum = e;
    for (int o = 32; o > 0; o >>= 1) ssum += __shfl_xor(ssum, o);
    attv[t] = e / ssum * 2.0f;   // * BETA
  }
  __syncthreads();
  for (int c = t; c < FEAT; c += 256){
    const float4* row = (const float4*)(fb + c*HW);
    float a2 = 0.f;
    #pragma unroll
    for (int k = 0; k < 16; ++k){
      float4 v4 = row[k];
      a2 = fmaf(v4.x, attv[k*4+0], a2);
      a2 = fmaf(v4.y, attv[k*4+1], a2);
      a2 = fmaf(v4.z, attv[k*4+2], a2);
      a2 = fmaf(v4.w, attv[k*4+3], a2);
    }
    att_feat[(size_t)b*FEAT + c] = __float2bfloat16(a2);
  }
}

// ---------------- bf16 MFMA GEMM (NT) for gi_base preamble ----------------
__global__ __launch_bounds__(256) void gemm_mfma(const bf16_t* __restrict__ A,
                                                 const bf16_t* __restrict__ W,
                                                 const float* __restrict__ bias,
                                                 float* __restrict__ C,
                                                 int K, int lda, int ldw, int ldc){
  const int tid = threadIdx.x;
  const int w = tid >> 6, lane = tid & 63;
  const int r = lane & 15, half = lane >> 4;
  const int m_base = blockIdx.y * 64;
  const int n_base = blockIdx.x * 64 + w * 16;
  const bf16_t* Ap = A + (size_t)(m_base + r)*lda + half*8;
  const bf16_t* Wp = W + (size_t)(n_base + r)*ldw + half*8;
  f32x4 acc[4] = {};
  for (int k0 = 0; k0 < K; k0 += 32){
    bf16x8 bfrag = *(const bf16x8*)(Wp + k0);
    #pragma unroll
    for (int i = 0; i < 4; ++i){
      bf16x8 afrag = *(const bf16x8*)(Ap + (size_t)i*16*lda + k0);
      acc[i] = MFMA(afrag, bfrag, acc[i]);
    }
  }
  const float bv = bias ? bias[n_base + r] : 0.f;
  #pragma unroll
  for (int i = 0; i < 4; ++i)
    #pragma unroll
    for (int q = 0; q < 4; ++q)
      C[(size_t)(m_base + i*16 + half*4 + q)*ldc + n_base + r] = acc[i][q] + bv;
}

// ---------------- the 32-step scan: mega13 re-tiled to 16 waves (4/SIMD) ----------------
// Identical chunks/swizzle/sync to the verified mega13 (1040us). Change: 1024
// threads = 16 waves; wave owns 32 h-cols (ti in {0,1}); 2 gld16/chunk/wave;
// WAITV(2) pacing. Doubles waves/SIMD to hide LDS latency under the pipeline.
__global__ __launch_bounds__(1024) void mega15_kernel(
    const float* __restrict__ gi_base,
    const bf16_t* __restrict__ sA,
    const bf16_t* __restrict__ sB,
    const bf16_t* __restrict__ sC,
    const bf16_t* __restrict__ w_ssn,
    const float* __restrict__ lin1_b,
    const float* __restrict__ lin2_b,
    const float* __restrict__ b_hh,
    const float* __restrict__ gt,
    const int* __restrict__ line_prob,
    const float* __restrict__ sample_prob,
    float* __restrict__ out){
  __shared__ bf16_t ring[3*CHW];         // 3 x 32KB, wave-sliced (2KB/wave/slot)
  __shared__ bf16_t lds_x[MB][LDX];      // [h(512) | ss(42) | zeros]
  __shared__ bf16_t o1s[MB][LDH];
  const int tid = threadIdx.x;
  const int wv = tid >> 6, l = tid & 63;
  const int lr = l & 15, half = l >> 4;
  const int m0 = blockIdx.x * MB;
  const int colbase = wv * 32;           // wave owns 32 h-cols
  const int rowoff = (colbase + lr)*32 + (half ^ ((lr >> 1) & 3))*8;  // + ti*512

  for (int i = tid; i < MB*LDX/2; i += 1024) ((uint32_t*)lds_x)[i] = 0u;

  // ---- register-resident gi_base slice: 2(ti) x 4(q) x 3 gates ----
  float gir[2][4], giz[2][4], gin_[2][4];
  #pragma unroll
  for (int ti = 0; ti < 2; ++ti)
    #pragma unroll
    for (int q = 0; q < 4; ++q){
      const float* gp = gi_base + (size_t)(m0 + half*4 + q)*G3 + colbase + ti*16 + lr;
      gir[ti][q]  = gp[0];
      giz[ti][q]  = gp[512];
      gin_[ti][q] = gp[1024];
    }
  float bhn[2], lb1[2];
  #pragma unroll
  for (int ti = 0; ti < 2; ++ti){
    bhn[ti] = b_hh[1024 + colbase + ti*16 + lr];
    lb1[ti] = lin1_b[colbase + ti*16 + lr];
  }
  const int j3 = wv*16 + lr;             // phase-C col (waves 0..2)
  const float b2c = (wv < 3 && j3 < OUTSZ) ? lin2_b[j3] : 0.f;
  bf16x8 sfr[2][2];
  #pragma unroll
  for (int ti = 0; ti < 2; ++ti)
    #pragma unroll
    for (int ks = 0; ks < 2; ++ks)
      sfr[ti][ks] = *(const bf16x8*)(w_ssn + (size_t)(colbase + ti*16 + lr)*64 + ks*32 + half*8);

  float hp[2][4] = {};

  // Per-wave slice issue: wave wv loads its 2KB (elements [wv*1024, +1024))
  // of chunk g into the same offsets of ring slot (g%3). 2 gld16 x 1KB.
  auto issue = [&](uint32_t g){
    const bf16_t* src = sA;              // dummy tail issues read sA
    if (g < (uint32_t)NL*CPS){
      uint32_t c = g % CPS;
      src = (c < 54) ? sA + (size_t)c*CHW
          : (c < 70) ? sB + (size_t)(c-54)*CHW
                     : sC + (size_t)(c-70)*CHW;
    }
    const int off = wv*1024 + l*8;
    const bf16_t* s = src + off;
    bf16_t* dst = ring + (g % 3)*CHW + off;
    gld16(s, dst);
    gld16(s + 512, dst + 512);
  };

  __syncthreads();                       // lds_x zero visible (prologue only)
  uint32_t gc = 0;
  issue(0); issue(1);

  #pragma unroll 1
  for (int t = 0; t < NL; ++t){
    // ============ phase A: 54 chunks, barrier-free, per-wave paced ============
    f32x4 accA[3][2] = {};
    #pragma unroll 1
    for (int k0 = 0; k0 < 18; ++k0){
      bf16x8 a = *(const bf16x8*)&lds_x[lr][k0*32 + half*8];
      #pragma unroll
      for (int g = 0; g < 3; ++g){
        WAITV2();                        // own chunk-gc loads landed
        issue(gc + 2);                   // own slice of slot(gc-1): private, free
        const bf16_t* S = ring + (gc % 3)*CHW;
        #pragma unroll
        for (int ti = 0; ti < 2; ++ti){
          bf16x8 bf = *(const bf16x8*)&S[rowoff + ti*512];
          accA[g][ti] = MFMA(a, bf, accA[g][ti]);
        }
        ++gc;
      }
    }

    // ---- ssn (weights in VGPRs; reads lds_x ss cols) ----
    f32x4 accS[2] = {};
    #pragma unroll
    for (int ks = 0; ks < 2; ++ks){
      bf16x8 a2 = *(const bf16x8*)&lds_x[lr][512 + ks*32 + half*8];
      #pragma unroll
      for (int ti = 0; ti < 2; ++ti)
        accS[ti] = MFMA(a2, sfr[ti][ks], accS[ti]);
    }
    PHASE_SYNC();    // (1) all waves' lds_x reads done before gates rewrite h

    // ---- gates ----
    #pragma unroll
    for (int ti = 0; ti < 2; ++ti)
      #pragma unroll
      for (int q = 0; q < 4; ++q){
        float ir = accA[0][ti][q] + gir[ti][q];
        float iz = accA[1][ti][q] + giz[ti][q];
        float hn = accA[2][ti][q] + bhn[ti];
        float gn = gin_[ti][q] + accS[ti][q];
        float r = sigmoidf_(ir);
        float z = sigmoidf_(iz);
        float n = tanhf(gn + r*hn);
        float hv = (1.f - z)*n + z*hp[ti][q];
        hp[ti][q] = hv;
        lds_x[half*4 + q][colbase + ti*16 + lr] = __float2bfloat16(hv);
      }
    PHASE_SYNC();    // (2) h visible to all waves

    // ============ phase B: 16 chunks, barrier-free, per-wave paced ============
    f32x4 accB[2] = {};
    #pragma unroll 1
    for (int cb = 0; cb < 16; ++cb){
      WAITV2();
      issue(gc + 2);                     // chunks 56..71: A/B slots, wave-private
      union { u16x8 u; bf16x8 b; } va;
      va.u = *(const u16x8*)&lds_x[lr][cb*32 + half*8];
      #pragma unroll
      for (int e = 0; e < 8; ++e)
        if (va.u[e] & 0x8000) va.u[e] = 0;       // relu on bf16 sign
      const bf16_t* S = ring + (gc % 3)*CHW;
      #pragma unroll
      for (int ti = 0; ti < 2; ++ti){
        bf16x8 bf = *(const bf16x8*)&S[rowoff + ti*512];
        accB[ti] = MFMA(va.b, bf, accB[ti]);
      }
      ++gc;
    }
    #pragma unroll
    for (int ti = 0; ti < 2; ++ti)
      #pragma unroll
      for (int q = 0; q < 4; ++q)
        o1s[half*4 + q][colbase + ti*16 + lr] =
            __float2bfloat16(fmaxf(accB[ti][q] + lb1[ti], 0.f));
    PHASE_SYNC_V0(); // (3) o1s visible AND all waves' C-chunk loads landed
                     //     (C chunks are consumed cross-slice by waves 0-2)

    // ============ phase C: 2 chunks (lin2), pre-drained, NO ISSUES ============
    f32x4 accC = {};
    #pragma unroll
    for (int n = 0; n < 2; ++n){
      if (wv < 3){
        const bf16_t* S = ring + (gc % 3)*CHW;
        #pragma unroll
        for (int k0 = 0; k0 < 8; ++k0){
          bf16x8 a = *(const bf16x8*)&o1s[lr][(n*8 + k0)*32 + half*8];
          int sg = (k0*4 + half) ^ (j3 & 7);
          bf16x8 bf = *(const bf16x8*)&S[j3*256 + sg*8];
          accC = MFMA(a, bf, accC);
        }
      }
      ++gc;
    }
    // outputs + ss_{t+1}
    if (wv < 3){
      #pragma unroll
      for (int q = 0; q < 4; ++q){
        float val = accC[q] + b2c;
        int row = half*4 + q;
        int bm = m0 + row;
        if (j3 < 40){
          out[((size_t)bm*NL + t)*40 + j3] = val;
        } else if (j3 < 42){
          float other = __shfl_xor(val, 1);
          float mx = fmaxf(val, other);
          float e0 = __expf(val - mx), e1 = __expf(other - mx);
          out[(size_t)B*NL*40 + ((size_t)bm*NL + t)*2 + (j3 - 40)] = e0/(e0 + e1);
        }
        if (t + 1 < NL && j3 < OUTSZ){
          bool up = sample_prob[(size_t)(t+1)*B + bm] < 0.1f;
          float gtv;
          if (j3 < 40) gtv = gt[((size_t)bm*NL + t)*40 + j3];
          else {
            float pv = (float)line_prob[bm*NL + t];
            gtv = (j3 == 40) ? 1.f - pv : pv;
          }
          lds_x[row][512 + j3] = __float2bfloat16(up ? val : gtv);
        }
      }
    }
    PHASE_SYNC();    // (4) ss visible; C readers drained -> slots 1,2 free
    issue(gc);       // next step's chunk 0 (slot 0; chunk 69's own-slice freed)
    issue(gc + 1);   // next step's chunk 1 (slot 1; chunk 70 readers drained)
  }
}

extern "C" void kernel_launch(void* const* d_in, const int* in_sizes, int n_in,
                              void* d_out, int out_size, void* d_ws, size_t ws_size,
                              hipStream_t stream) {
  const float* img         = (const float*)d_in[0];
  const float* gt          = (const float*)d_in[1];
  const int*   line_prob   = (const int*)d_in[2];
  const float* sample_prob = (const float*)d_in[3];
  const float* att_w       = (const float*)d_in[4];
  // d_in[5] att_b: unused — softmax shift-invariance cancels it
  const float* w_ih        = (const float*)d_in[6];
  const float* w_hh        = (const float*)d_in[7];
  const float* b_ih        = (const float*)d_in[8];
  const float* b_hh        = (const float*)d_in[9];
  const float* lin1_w      = (const float*)d_in[10];
  const float* lin1_b      = (const float*)d_in[11];
  const float* lin2_w      = (const float*)d_in[12];
  const float* lin2_b      = (const float*)d_in[13];
  float* out = (float*)d_out;

  char* p = (char*)d_ws;
  auto alloc = [&](size_t bytes){ void* q = p; p += (bytes + 255) & ~(size_t)255; return q; };
  float*  gi_base   = (float*)alloc((size_t)B*G3*4);
  bf16_t* att_bf    = (bf16_t*)alloc((size_t)B*FEAT*2);
  bf16_t* sA        = (bf16_t*)alloc((size_t)54*CHW*2);
  bf16_t* sB        = (bf16_t*)alloc((size_t)16*CHW*2);
  bf16_t* sC        = (bf16_t*)alloc((size_t)2*CHW*2);
  bf16_t* w_ssn     = (bf16_t*)alloc((size_t)512*64*2);
  bf16_t* w_ih512b  = (bf16_t*)alloc((size_t)G3*512*2);
  float*  bias_comb = (float*)alloc((size_t)G3*4);

  prep4_kernel<<<4096, 256, 0, stream>>>(w_ih, w_hh, lin1_w, lin2_w, b_ih, b_hh,
                                         sA, sB, sC, w_ssn, w_ih512b, bias_comb);
  att_kernel<<<B, 256, 0, stream>>>(img, att_w, att_bf);
  gemm_mfma<<<dim3(G3/64, B/64), 256, 0, stream>>>(att_bf, w_ih512b, bias_comb, gi_base,
                                                   512, 512, 512, G3);
  mega15_kernel<<<NBLK, 1024, 0, stream>>>(gi_base, sA, sB, sC, w_ssn, lin1_b, lin2_b,
                                           b_hh, gt, line_prob, sample_prob, out);
}